// Round 1
// baseline (387.644 us; speedup 1.0000x reference)
//
#include <hip/hip_runtime.h>

// Problem constants (from reference)
#define HH 4096
#define WW 4096
#define NB 1024
#define NCHUNK 256
#define CROWS 16          // HH / NCHUNK
#define IOU_T 0.5f
#define NBLK_STAGE 1024   // (NCHUNK * WW / 4) / 256
#define NBLK_TAIL 64

typedef unsigned long long u64;

// ---------------- workspace layout ------------------------------------------
constexpr size_t OFF_PART   = 0;                                   // double x NCHUNK*WW (8 MB)
constexpr size_t OFF_SC64   = OFF_PART   + (size_t)NCHUNK * WW * 8;// double x NB
constexpr size_t OFF_ORDER  = OFF_SC64   + (size_t)NB * 8;         // int x NB
constexpr size_t OFF_CTR    = OFF_ORDER  + (size_t)NB * 4;         // int[2] (64 B pad): [0]=arrival, [1]=barrier
constexpr size_t OFF_IOU    = OFF_CTR    + 64;                     // u64 x NB*16 (128 KB)
constexpr size_t OFF_RECSC  = OFF_IOU    + (size_t)NB * 16 * 8;    // double x NB
constexpr size_t OFF_RECSEL = OFF_RECSC  + (size_t)NB * 8;         // u64 x NB*16 (128 KB)
constexpr size_t OFF_CC     = OFF_RECSEL + (size_t)NB * 16 * 8;    // float x HH*WW (64 MB)
// total ~= 72.5 MB

// ---------------- device-scope grid barrier for k_tail (64 co-resident blocks)
__device__ __forceinline__ void gbar(int* bctr, int round) {
    __threadfence();                  // all threads: release block's global writes
    __syncthreads();
    if (threadIdx.x == 0) {
        __hip_atomic_fetch_add(bctr, 1, __ATOMIC_ACQ_REL, __HIP_MEMORY_SCOPE_AGENT);
        while (__hip_atomic_load(bctr, __ATOMIC_ACQUIRE, __HIP_MEMORY_SCOPE_AGENT)
               < NBLK_TAIL * round)
            __builtin_amdgcn_s_sleep(2);
    }
    __syncthreads();
    __threadfence();                  // all threads: acquire (drop stale L1)
}

// ---------------- kernels ---------------------------------------------------

// fused staging + chunk scan. Staging body unchanged from R13 (verified):
// each block owns one chunk of 16 rows x 1024 cols; derives row x-range
// unions from bbox via LDS atomics; ONE read of probs, float4 loads;
// 1024 blocks = 4 waves/SIMD device-wide.
// NEW: the column-direction exclusive scan of `part` (formerly k_chunkscan)
// is performed by the LAST 64 blocks to finish staging: every block bumps a
// device-scope arrival counter; arrivals >= 960 become scan workers, spin
// until all 1024 arrived, then scan 64 columns each (1 col/lane of wave 0,
// coalesced — identical access pattern to the old kernel). Deadlock-free:
// workers are resident by construction, non-workers retire and free slots.
__global__ void __launch_bounds__(256) k_stage(const float* __restrict__ probs,
        const float* __restrict__ bbox,
        double* __restrict__ part, float* __restrict__ Cc, int* __restrict__ ctrs) {
    __shared__ int xlo_s[CROWS], xhi_s[CROWS];
    __shared__ int2 rng_s[CROWS];   // {q0, q1} col-quad range; {1,0} if unflagged
    __shared__ int sIdx;
    int tid = blockIdx.x * 256 + threadIdx.x;   // NCHUNK * WW/4 threads
    int c  = tid >> 10;          // chunk (uniform per block)
    int xq = tid & 1023;         // col-quad index
    int t  = threadIdx.x;
    if (t < CROWS) { xlo_s[t] = WW + 1; xhi_s[t] = -1; }
    __syncthreads();
    int r0 = c * CROWS;
    for (int i = t; i < NB; i += 256) {
        float4 bb = ((const float4*)bbox)[i];
        int x1 = min(max((int)floorf(bb.x), 0), WW);
        int y1 = min(max((int)floorf(bb.y), 0), HH);
        int x2 = min(max((int)floorf(bb.z), 0), WW);
        int y2 = min(max((int)floorf(bb.w), 0), HH);
        int ra = y1 - 1 - r0, rb = y2 - 1 - r0;
        if (ra >= 0 && ra < CROWS) { atomicMin(&xlo_s[ra], x1); atomicMax(&xhi_s[ra], x2); }
        if (rb >= 0 && rb < CROWS) { atomicMin(&xlo_s[rb], x1); atomicMax(&xhi_s[rb], x2); }
    }
    __syncthreads();
    if (t < CROWS) {
        int lo = xlo_s[t], hi = xhi_s[t];
        rng_s[t] = (hi >= 0) ? make_int2(lo >> 2, (hi + 3) >> 2) : make_int2(1, 0);
    }
    __syncthreads();
    const float4* p = (const float4*)probs + (size_t)r0 * (WW / 4) + xq;
    float4* Cc4 = (float4*)Cc;
    double a0 = 0.0, a1 = 0.0, a2 = 0.0, a3 = 0.0;
    for (int r = 0; r < CROWS; r += 8) {
        float4 q[8];
        #pragma unroll
        for (int k = 0; k < 8; k++) q[k] = p[(size_t)(r + k) * (WW / 4)];
        #pragma unroll
        for (int k = 0; k < 8; k++) {
            a0 += (double)q[k].x; a1 += (double)q[k].y;
            a2 += (double)q[k].z; a3 += (double)q[k].w;
            int2 d = rng_s[r + k];
            if (xq >= d.x && xq < d.y)
                Cc4[(size_t)(r0 + r + k) * (WW / 4) + xq] =
                    make_float4((float)a0, (float)a1, (float)a2, (float)a3);
        }
    }
    double2* pp = (double2*)(part + (size_t)c * WW) + xq * 2;
    pp[0] = make_double2(a0, a1);
    pp[1] = make_double2(a2, a3);

    // ---- fused chunk scan (last-64-arrival workers) ----
    __threadfence();               // release this block's part writes
    __syncthreads();
    if (t == 0) sIdx = atomicAdd(&ctrs[0], 1);
    __syncthreads();
    int w = sIdx - (NBLK_STAGE - NBLK_TAIL);
    if (w < 0) return;             // non-worker: retire, free the CU slot
    if (t == 0) {
        while (__hip_atomic_load(&ctrs[0], __ATOMIC_ACQUIRE, __HIP_MEMORY_SCOPE_AGENT)
               < NBLK_STAGE)
            __builtin_amdgcn_s_sleep(2);
    }
    __syncthreads();
    __threadfence();               // acquire: all blocks' part writes visible
    if (t < 64) {
        int x = w * 64 + t;        // 64 workers x 64 lanes = 4096 columns
        double carry = 0.0;
        for (int g = 0; g < NCHUNK / 16; g++) {
            double v[16];
            #pragma unroll
            for (int k = 0; k < 16; k++) v[k] = part[(size_t)(g * 16 + k) * WW + x];
            #pragma unroll
            for (int k = 0; k < 16; k++) { double tv = v[k]; v[k] = carry; carry += tv; }
            #pragma unroll
            for (int k = 0; k < 16; k++) part[(size_t)(g * 16 + k) * WW + x] = v[k];
        }
    }
}

// fused tail: boxsum -> rank -> iou -> group -> final, one kernel, 64 blocks
// x 256 threads (always co-resident on 256 CUs -> spin barriers are safe).
// Sorted scores / order / sorted bboxes cached in LDS across phases.
__global__ void __launch_bounds__(256) k_tail(const float* __restrict__ bbox,
        const float* __restrict__ obj,
        const float* __restrict__ Cc,
        const double* __restrict__ part,
        const int* __restrict__ counts,
        double* __restrict__ sc64, int* __restrict__ order,
        u64* __restrict__ ioub, double* __restrict__ recsc,
        u64* __restrict__ recsel, int* __restrict__ ctrs,
        float* __restrict__ out) {
    __shared__ double s_sc[NB];     // 8 KB, unsorted scores (P2..P5)
    __shared__ int    ord_s[NB];    // 4 KB, sorted->orig index (P3..P5)
    __shared__ float4 sbb[NB];      // 16 KB, sorted bboxes (P3)
    __shared__ int    rnk[16];
    int b = blockIdx.x, t = threadIdx.x;
    int* bctr = &ctrs[1];

    // ---- P1: boxsum (16 boxes/block, one wave per box, 4 boxes sequential).
    // column value = within-chunk fp32 cumsum row + fp64 chunk prefix.
    {
        int wv = t >> 6, l = t & 63;
        for (int q = 0; q < 4; q++) {
            int i = b * 16 + wv * 4 + q;
            float4 bb = ((const float4*)bbox)[i];
            int x1 = min(max((int)floorf(bb.x), 0), WW);
            int y1 = min(max((int)floorf(bb.y), 0), HH);
            int x2 = min(max((int)floorf(bb.z), 0), WW);
            int y2 = min(max((int)floorf(bb.w), 0), HH);
            bool h1 = (y1 >= 1), h2 = (y2 >= 1);
            const float*  r2 = Cc   + (size_t)(h2 ? (y2 - 1) : 0) * WW;
            const double* q2 = part + (size_t)(h2 ? ((y2 - 1) >> 4) : 0) * WW;
            const float*  r1 = Cc   + (size_t)(h1 ? (y1 - 1) : 0) * WW;
            const double* q1 = part + (size_t)(h1 ? ((y1 - 1) >> 4) : 0) * WW;
            double s = 0.0;
            for (int x = x1 + l; x < x2; x += 64) {
                double v2 = h2 ? ((double)r2[x] + q2[x]) : 0.0;
                double v1 = h1 ? ((double)r1[x] + q1[x]) : 0.0;
                s += (v2 - v1);
            }
            #pragma unroll
            for (int off = 32; off > 0; off >>= 1) s += __shfl_down(s, off);
            if (l == 0) {
                long long cnt = (long long)(y2 - y1) * (long long)(x2 - x1);
                if (cnt < 1) cnt = 1;
                sc64[i] = 0.5 * ((double)obj[i] + s / (double)cnt);
            }
        }
    }
    gbar(bctr, 1);

    // ---- P2: stable descending rank (16 boxes/block, 16 threads per box,
    // 5*g stagger breaks the stride-64-double 16-way LDS bank conflict).
    for (int k = t; k < NB; k += 256) s_sc[k] = sc64[k];
    if (t < 16) rnk[t] = 0;
    __syncthreads();
    {
        int q = t >> 4;             // box slot 0..15
        int g = t & 15;             // j-chunk 0..15
        int i = b * 16 + q;
        double si = s_sc[i];
        int p = 0;
        for (int it = 0; it < 64; it++) {
            int j = (g << 6) + ((it + 5 * g) & 63);
            double sj = s_sc[j];
            p += (sj > si) || (sj == si && j < i);
        }
        atomicAdd(&rnk[q], p);
    }
    __syncthreads();
    if (t < 16) order[rnk[t]] = b * 16 + t;
    gbar(bctr, 2);

    // ---- P3: IoU(sorted_i, sorted_j) > 0.5 bit matrix; 16 rows/block,
    // sorted bboxes gathered once into LDS then reused 64x.
    for (int k = t; k < NB; k += 256) {
        int o = order[k];
        ord_s[k] = o;
        sbb[k] = ((const float4*)bbox)[o];
    }
    __syncthreads();
    {
        int wv = t >> 6, l = t & 63;
        for (int rr = 0; rr < 4; rr++) {
            int i = b * 16 + wv * 4 + rr;
            float4 a = sbb[i];
            float ai = (a.z - a.x) * (a.w - a.y);
            for (int wd = 0; wd < 16; wd++) {
                float4 bb = sbb[(wd << 6) + l];
                float aj = (bb.z - bb.x) * (bb.w - bb.y);
                float ix1 = fmaxf(a.x, bb.x), iy1 = fmaxf(a.y, bb.y);
                float ix2 = fminf(a.z, bb.z), iy2 = fminf(a.w, bb.w);
                float iw = fmaxf(ix2 - ix1, 0.0f), ih = fmaxf(iy2 - iy1, 0.0f);
                float inter = iw * ih;
                float iou_v = inter / (ai + aj - inter);
                u64 m = __ballot(iou_v > IOU_T);
                if (l == 0) ioub[(size_t)i * 16 + wd] = m;
            }
        }
    }
    gbar(bctr, 3);

    // ---- P4: greedy grouping (16 starts/block, lanes 0..15 of wave 0).
    // Register masks + ctz scan walk the SAME increasing-j greedy order as
    // the reference (inc updated per add). Record rule: rec iff size==K and
    // the last add happened at j <= NB-2 (check-before-add semantics).
    {
        int K = counts[0];
        if (t < 16) {
            int i = b * 16 + t;
            u64 inc[16], sel[16];
            int wi = i >> 6, bi = i & 63;
            #pragma unroll
            for (int w = 0; w < 16; w++) {
                inc[w] = ioub[(size_t)i * 16 + w];
                sel[w] = (w == wi) ? (1ULL << bi) : 0ULL;
            }
            int size = 1;
            double score = s_sc[ord_s[i]];
            int last = i;
            #pragma unroll
            for (int w = 0; w < 16; w++) {
                if (w < wi || size >= K) continue;
                u64 avail = ~inc[w];
                if (w == wi) avail &= (bi == 63) ? 0ULL : (~0ULL << (bi + 1));
                while (avail != 0ULL && size < K) {
                    int bj = __builtin_ctzll(avail);
                    int j = (w << 6) + bj;
                    sel[w] |= 1ULL << bj;
                    size++;
                    score += s_sc[ord_s[j]];
                    last = j;
                    const u64* rj = ioub + (size_t)j * 16;
                    #pragma unroll
                    for (int w2 = 0; w2 < 16; w2++) inc[w2] |= rj[w2];
                    avail &= ~inc[w];          // row j's own bits clear bj et al.
                    avail &= ~(1ULL << bj);    // safety
                }
            }
            int rec = (size == K) && (last < NB - 1);
            recsc[i] = rec ? score : -1e300;
            #pragma unroll
            for (int w = 0; w < 16; w++) recsel[(size_t)i * 16 + w] = sel[w];
        }
    }
    gbar(bctr, 4);
    if (b != 0) return;

    // ---- P5: final last-argmax + output scatter (block 0, wave 0).
    if (t < 64) {
        double bs = -1e301; int bidx = 0;
        for (int m = 0; m < 16; m++) {
            int k = t * 16 + m;        // increasing k; >= keeps the last
            double v = recsc[k];
            if (v >= bs) { bs = v; bidx = k; }
        }
        #pragma unroll
        for (int off = 32; off > 0; off >>= 1) {
            double ob = __shfl_down(bs, off);
            int oi = __shfl_down(bidx, off);
            if (ob > bs || (ob == bs && oi > bidx)) { bs = ob; bidx = oi; }
        }
        bs = __shfl(bs, 0);
        bidx = __shfl(bidx, 0);
        int any = bs > -1e299;
        for (int k = t; k < NB; k += 64) {
            float v = 0.0f;
            if (any && ((recsel[(size_t)bidx * 16 + (k >> 6)] >> (k & 63)) & 1ULL))
                v = (float)s_sc[ord_s[k]];
            out[k] = v;
        }
    }
}

// ---------------- host entry ------------------------------------------------

extern "C" void kernel_launch(void* const* d_in, const int* in_sizes, int n_in,
                              void* d_out, int out_size, void* d_ws, size_t ws_size,
                              hipStream_t stream) {
    const float* bbox  = (const float*)d_in[0];
    const float* obj   = (const float*)d_in[1];
    const float* probs = (const float*)d_in[2];
    const int*   counts = (const int*)d_in[3];
    float* out = (float*)d_out;

    char* w = (char*)d_ws;
    double* part    = (double*)(w + OFF_PART);
    double* sc64    = (double*)(w + OFF_SC64);
    int*    order   = (int*)(w + OFF_ORDER);
    int*    ctrs    = (int*)(w + OFF_CTR);
    u64*    ioub    = (u64*)(w + OFF_IOU);
    double* recsc   = (double*)(w + OFF_RECSC);
    u64*    recsel  = (u64*)(w + OFF_RECSEL);
    float*  Cc      = (float*)(w + OFF_CC);

    hipMemsetAsync(w + OFF_CTR, 0, 64, stream);   // arrival + barrier counters
    k_stage<<<NBLK_STAGE, 256, 0, stream>>>(probs, bbox, part, Cc, ctrs);
    k_tail<<<NBLK_TAIL, 256, 0, stream>>>(bbox, obj, Cc, part, counts,
                                          sc64, order, ioub, recsc, recsel,
                                          ctrs, out);
}

// Round 2
// 223.514 us; speedup vs baseline: 1.7343x; 1.7343x over previous
//
#include <hip/hip_runtime.h>

// Problem constants (from reference)
#define HH 4096
#define WW 4096
#define NB 1024
#define NCHUNK 256
#define CROWS 16          // HH / NCHUNK
#define IOU_T 0.5f
#define NBLK_STAGE 1024   // (NCHUNK * WW / 4) / 256
#define NBLK_TAIL 64

typedef unsigned long long u64;

// ---------------- workspace layout ------------------------------------------
constexpr size_t OFF_PART   = 0;                                   // double x NCHUNK*WW (8 MB)
constexpr size_t OFF_SC64   = OFF_PART   + (size_t)NCHUNK * WW * 8;// double x NB
constexpr size_t OFF_ORDER  = OFF_SC64   + (size_t)NB * 8;         // int x NB
constexpr size_t OFF_CTR    = OFF_ORDER  + (size_t)NB * 4;         // int[2] (64 B pad): [0]=arrival, [1]=barrier
constexpr size_t OFF_IOU    = OFF_CTR    + 64;                     // u64 x NB*16 (128 KB)
constexpr size_t OFF_RECSC  = OFF_IOU    + (size_t)NB * 16 * 8;    // double x NB
constexpr size_t OFF_RECSEL = OFF_RECSC  + (size_t)NB * 8;         // u64 x NB*16 (128 KB)
constexpr size_t OFF_CC     = OFF_RECSEL + (size_t)NB * 16 * 8;    // float x HH*WW (64 MB)
// total ~= 72.5 MB

// ---------------- device-scope grid barrier for k_tail (64 co-resident blocks)
// R2: RELAXED polling (no cache maintenance per poll!) + ONE release RMW on
// entry + ONE acquire RMW on exit, all by thread 0. R1's ACQUIRE-scope poll
// emitted buffer_inv (L2 invalidate) EVERY iteration, continuously wiping the
// XCD L2 under the streaming blocks -> 271 GB/s, 15x regression.
__device__ __forceinline__ void gbar(int* bctr, int round) {
    __syncthreads();   // drains this block's vmem writes (compiler waitcnt)
    if (threadIdx.x == 0) {
        // release: one buffer_wbl2 flushes this XCD's L2 (L1 is write-through,
        // so after __syncthreads all block writes are in L2).
        __hip_atomic_fetch_add(bctr, 1, __ATOMIC_RELEASE, __HIP_MEMORY_SCOPE_AGENT);
        while (__hip_atomic_load(bctr, __ATOMIC_RELAXED, __HIP_MEMORY_SCOPE_AGENT)
               < NBLK_TAIL * round)
            __builtin_amdgcn_s_sleep(4);
        // acquire: one buffer_inv makes all other blocks' writes visible to
        // this CU's subsequent reads.
        __hip_atomic_fetch_add(bctr, 0, __ATOMIC_ACQUIRE, __HIP_MEMORY_SCOPE_AGENT);
    }
    __syncthreads();
}

// ---------------- kernels ---------------------------------------------------

// fused staging + chunk scan. Staging body unchanged from R13 (verified):
// each block owns one chunk of 16 rows x 1024 cols; derives row x-range
// unions from bbox via LDS atomics; ONE read of probs, float4 loads;
// 1024 blocks = 4 waves/SIMD device-wide.
// Column-direction exclusive scan of `part` (formerly k_chunkscan) is done by
// the LAST 64 blocks to arrive (all 1024 blocks are co-resident at 4/CU, so
// the wait is just execution skew). Sync per R2 scheme above.
__global__ void __launch_bounds__(256) k_stage(const float* __restrict__ probs,
        const float* __restrict__ bbox,
        double* __restrict__ part, float* __restrict__ Cc, int* __restrict__ ctrs) {
    __shared__ int xlo_s[CROWS], xhi_s[CROWS];
    __shared__ int2 rng_s[CROWS];   // {q0, q1} col-quad range; {1,0} if unflagged
    __shared__ int sIdx;
    int tid = blockIdx.x * 256 + threadIdx.x;   // NCHUNK * WW/4 threads
    int c  = tid >> 10;          // chunk (uniform per block)
    int xq = tid & 1023;         // col-quad index
    int t  = threadIdx.x;
    if (t < CROWS) { xlo_s[t] = WW + 1; xhi_s[t] = -1; }
    __syncthreads();
    int r0 = c * CROWS;
    for (int i = t; i < NB; i += 256) {
        float4 bb = ((const float4*)bbox)[i];
        int x1 = min(max((int)floorf(bb.x), 0), WW);
        int y1 = min(max((int)floorf(bb.y), 0), HH);
        int x2 = min(max((int)floorf(bb.z), 0), WW);
        int y2 = min(max((int)floorf(bb.w), 0), HH);
        int ra = y1 - 1 - r0, rb = y2 - 1 - r0;
        if (ra >= 0 && ra < CROWS) { atomicMin(&xlo_s[ra], x1); atomicMax(&xhi_s[ra], x2); }
        if (rb >= 0 && rb < CROWS) { atomicMin(&xlo_s[rb], x1); atomicMax(&xhi_s[rb], x2); }
    }
    __syncthreads();
    if (t < CROWS) {
        int lo = xlo_s[t], hi = xhi_s[t];
        rng_s[t] = (hi >= 0) ? make_int2(lo >> 2, (hi + 3) >> 2) : make_int2(1, 0);
    }
    __syncthreads();
    const float4* p = (const float4*)probs + (size_t)r0 * (WW / 4) + xq;
    float4* Cc4 = (float4*)Cc;
    double a0 = 0.0, a1 = 0.0, a2 = 0.0, a3 = 0.0;
    for (int r = 0; r < CROWS; r += 8) {
        float4 q[8];
        #pragma unroll
        for (int k = 0; k < 8; k++) q[k] = p[(size_t)(r + k) * (WW / 4)];
        #pragma unroll
        for (int k = 0; k < 8; k++) {
            a0 += (double)q[k].x; a1 += (double)q[k].y;
            a2 += (double)q[k].z; a3 += (double)q[k].w;
            int2 d = rng_s[r + k];
            if (xq >= d.x && xq < d.y)
                Cc4[(size_t)(r0 + r + k) * (WW / 4) + xq] =
                    make_float4((float)a0, (float)a1, (float)a2, (float)a3);
        }
    }
    double2* pp = (double2*)(part + (size_t)c * WW) + xq * 2;
    pp[0] = make_double2(a0, a1);
    pp[1] = make_double2(a2, a3);

    // ---- fused chunk scan (last-64-arrival workers) ----
    __syncthreads();               // drain part/Cc writes to L2
    if (t == 0)
        sIdx = __hip_atomic_fetch_add(&ctrs[0], 1, __ATOMIC_RELEASE,
                                      __HIP_MEMORY_SCOPE_AGENT);
    __syncthreads();
    int w = sIdx - (NBLK_STAGE - NBLK_TAIL);
    if (w < 0) return;             // non-worker: retire
    if (t == 0) {
        while (__hip_atomic_load(&ctrs[0], __ATOMIC_RELAXED, __HIP_MEMORY_SCOPE_AGENT)
               < NBLK_STAGE)
            __builtin_amdgcn_s_sleep(4);
        __hip_atomic_fetch_add(&ctrs[0], 0, __ATOMIC_ACQUIRE,
                               __HIP_MEMORY_SCOPE_AGENT);
    }
    __syncthreads();
    if (t < 64) {
        int x = w * 64 + t;        // 64 workers x 64 lanes = 4096 columns
        double carry = 0.0;
        for (int g = 0; g < NCHUNK / 16; g++) {
            double v[16];
            #pragma unroll
            for (int k = 0; k < 16; k++) v[k] = part[(size_t)(g * 16 + k) * WW + x];
            #pragma unroll
            for (int k = 0; k < 16; k++) { double tv = v[k]; v[k] = carry; carry += tv; }
            #pragma unroll
            for (int k = 0; k < 16; k++) part[(size_t)(g * 16 + k) * WW + x] = v[k];
        }
    }
}

// fused tail: boxsum -> rank -> iou -> group -> final, one kernel, 64 blocks
// x 256 threads (always co-resident on 256 CUs -> spin barriers are safe).
// Sorted scores / order / sorted bboxes cached in LDS across phases.
__global__ void __launch_bounds__(256) k_tail(const float* __restrict__ bbox,
        const float* __restrict__ obj,
        const float* __restrict__ Cc,
        const double* __restrict__ part,
        const int* __restrict__ counts,
        double* __restrict__ sc64, int* __restrict__ order,
        u64* __restrict__ ioub, double* __restrict__ recsc,
        u64* __restrict__ recsel, int* __restrict__ ctrs,
        float* __restrict__ out) {
    __shared__ double s_sc[NB];     // 8 KB, unsorted scores (P2..P5)
    __shared__ int    ord_s[NB];    // 4 KB, sorted->orig index (P3..P5)
    __shared__ float4 sbb[NB];      // 16 KB, sorted bboxes (P3)
    __shared__ int    rnk[16];
    int b = blockIdx.x, t = threadIdx.x;
    int* bctr = &ctrs[1];

    // ---- P1: boxsum (16 boxes/block, one wave per box, 4 boxes sequential).
    // column value = within-chunk fp32 cumsum row + fp64 chunk prefix.
    {
        int wv = t >> 6, l = t & 63;
        for (int q = 0; q < 4; q++) {
            int i = b * 16 + wv * 4 + q;
            float4 bb = ((const float4*)bbox)[i];
            int x1 = min(max((int)floorf(bb.x), 0), WW);
            int y1 = min(max((int)floorf(bb.y), 0), HH);
            int x2 = min(max((int)floorf(bb.z), 0), WW);
            int y2 = min(max((int)floorf(bb.w), 0), HH);
            bool h1 = (y1 >= 1), h2 = (y2 >= 1);
            const float*  r2 = Cc   + (size_t)(h2 ? (y2 - 1) : 0) * WW;
            const double* q2 = part + (size_t)(h2 ? ((y2 - 1) >> 4) : 0) * WW;
            const float*  r1 = Cc   + (size_t)(h1 ? (y1 - 1) : 0) * WW;
            const double* q1 = part + (size_t)(h1 ? ((y1 - 1) >> 4) : 0) * WW;
            double s = 0.0;
            for (int x = x1 + l; x < x2; x += 64) {
                double v2 = h2 ? ((double)r2[x] + q2[x]) : 0.0;
                double v1 = h1 ? ((double)r1[x] + q1[x]) : 0.0;
                s += (v2 - v1);
            }
            #pragma unroll
            for (int off = 32; off > 0; off >>= 1) s += __shfl_down(s, off);
            if (l == 0) {
                long long cnt = (long long)(y2 - y1) * (long long)(x2 - x1);
                if (cnt < 1) cnt = 1;
                sc64[i] = 0.5 * ((double)obj[i] + s / (double)cnt);
            }
        }
    }
    gbar(bctr, 1);

    // ---- P2: stable descending rank (16 boxes/block, 16 threads per box,
    // 5*g stagger breaks the stride-64-double 16-way LDS bank conflict).
    for (int k = t; k < NB; k += 256) s_sc[k] = sc64[k];
    if (t < 16) rnk[t] = 0;
    __syncthreads();
    {
        int q = t >> 4;             // box slot 0..15
        int g = t & 15;             // j-chunk 0..15
        int i = b * 16 + q;
        double si = s_sc[i];
        int p = 0;
        for (int it = 0; it < 64; it++) {
            int j = (g << 6) + ((it + 5 * g) & 63);
            double sj = s_sc[j];
            p += (sj > si) || (sj == si && j < i);
        }
        atomicAdd(&rnk[q], p);
    }
    __syncthreads();
    if (t < 16) order[rnk[t]] = b * 16 + t;
    gbar(bctr, 2);

    // ---- P3: IoU(sorted_i, sorted_j) > 0.5 bit matrix; 16 rows/block,
    // sorted bboxes gathered once into LDS then reused 64x.
    for (int k = t; k < NB; k += 256) {
        int o = order[k];
        ord_s[k] = o;
        sbb[k] = ((const float4*)bbox)[o];
    }
    __syncthreads();
    {
        int wv = t >> 6, l = t & 63;
        for (int rr = 0; rr < 4; rr++) {
            int i = b * 16 + wv * 4 + rr;
            float4 a = sbb[i];
            float ai = (a.z - a.x) * (a.w - a.y);
            for (int wd = 0; wd < 16; wd++) {
                float4 bb = sbb[(wd << 6) + l];
                float aj = (bb.z - bb.x) * (bb.w - bb.y);
                float ix1 = fmaxf(a.x, bb.x), iy1 = fmaxf(a.y, bb.y);
                float ix2 = fminf(a.z, bb.z), iy2 = fminf(a.w, bb.w);
                float iw = fmaxf(ix2 - ix1, 0.0f), ih = fmaxf(iy2 - iy1, 0.0f);
                float inter = iw * ih;
                float iou_v = inter / (ai + aj - inter);
                u64 m = __ballot(iou_v > IOU_T);
                if (l == 0) ioub[(size_t)i * 16 + wd] = m;
            }
        }
    }
    gbar(bctr, 3);

    // ---- P4: greedy grouping (16 starts/block, lanes 0..15 of wave 0).
    // Register masks + ctz scan walk the SAME increasing-j greedy order as
    // the reference (inc updated per add). Record rule: rec iff size==K and
    // the last add happened at j <= NB-2 (check-before-add semantics).
    {
        int K = counts[0];
        if (t < 16) {
            int i = b * 16 + t;
            u64 inc[16], sel[16];
            int wi = i >> 6, bi = i & 63;
            #pragma unroll
            for (int w = 0; w < 16; w++) {
                inc[w] = ioub[(size_t)i * 16 + w];
                sel[w] = (w == wi) ? (1ULL << bi) : 0ULL;
            }
            int size = 1;
            double score = s_sc[ord_s[i]];
            int last = i;
            #pragma unroll
            for (int w = 0; w < 16; w++) {
                if (w < wi || size >= K) continue;
                u64 avail = ~inc[w];
                if (w == wi) avail &= (bi == 63) ? 0ULL : (~0ULL << (bi + 1));
                while (avail != 0ULL && size < K) {
                    int bj = __builtin_ctzll(avail);
                    int j = (w << 6) + bj;
                    sel[w] |= 1ULL << bj;
                    size++;
                    score += s_sc[ord_s[j]];
                    last = j;
                    const u64* rj = ioub + (size_t)j * 16;
                    #pragma unroll
                    for (int w2 = 0; w2 < 16; w2++) inc[w2] |= rj[w2];
                    avail &= ~inc[w];          // row j's own bits clear bj et al.
                    avail &= ~(1ULL << bj);    // safety
                }
            }
            int rec = (size == K) && (last < NB - 1);
            recsc[i] = rec ? score : -1e300;
            #pragma unroll
            for (int w = 0; w < 16; w++) recsel[(size_t)i * 16 + w] = sel[w];
        }
    }
    gbar(bctr, 4);
    if (b != 0) return;

    // ---- P5: final last-argmax + output scatter (block 0, wave 0).
    if (t < 64) {
        double bs = -1e301; int bidx = 0;
        for (int m = 0; m < 16; m++) {
            int k = t * 16 + m;        // increasing k; >= keeps the last
            double v = recsc[k];
            if (v >= bs) { bs = v; bidx = k; }
        }
        #pragma unroll
        for (int off = 32; off > 0; off >>= 1) {
            double ob = __shfl_down(bs, off);
            int oi = __shfl_down(bidx, off);
            if (ob > bs || (ob == bs && oi > bidx)) { bs = ob; bidx = oi; }
        }
        bs = __shfl(bs, 0);
        bidx = __shfl(bidx, 0);
        int any = bs > -1e299;
        for (int k = t; k < NB; k += 64) {
            float v = 0.0f;
            if (any && ((recsel[(size_t)bidx * 16 + (k >> 6)] >> (k & 63)) & 1ULL))
                v = (float)s_sc[ord_s[k]];
            out[k] = v;
        }
    }
}

// ---------------- host entry ------------------------------------------------

extern "C" void kernel_launch(void* const* d_in, const int* in_sizes, int n_in,
                              void* d_out, int out_size, void* d_ws, size_t ws_size,
                              hipStream_t stream) {
    const float* bbox  = (const float*)d_in[0];
    const float* obj   = (const float*)d_in[1];
    const float* probs = (const float*)d_in[2];
    const int*   counts = (const int*)d_in[3];
    float* out = (float*)d_out;

    char* w = (char*)d_ws;
    double* part    = (double*)(w + OFF_PART);
    double* sc64    = (double*)(w + OFF_SC64);
    int*    order   = (int*)(w + OFF_ORDER);
    int*    ctrs    = (int*)(w + OFF_CTR);
    u64*    ioub    = (u64*)(w + OFF_IOU);
    double* recsc   = (double*)(w + OFF_RECSC);
    u64*    recsel  = (u64*)(w + OFF_RECSEL);
    float*  Cc      = (float*)(w + OFF_CC);

    hipMemsetAsync(w + OFF_CTR, 0, 64, stream);   // arrival + barrier counters
    k_stage<<<NBLK_STAGE, 256, 0, stream>>>(probs, bbox, part, Cc, ctrs);
    k_tail<<<NBLK_TAIL, 256, 0, stream>>>(bbox, obj, Cc, part, counts,
                                          sc64, order, ioub, recsc, recsel,
                                          ctrs, out);
}

// Round 3
// 190.504 us; speedup vs baseline: 2.0348x; 1.1733x over previous
//
#include <hip/hip_runtime.h>

// Problem constants (from reference)
#define HH 4096
#define WW 4096
#define NB 1024
#define NCHUNK 256
#define CROWS 16          // HH / NCHUNK
#define IOU_T 0.5f
#define NBLK_STAGE 1024   // (NCHUNK * WW / 4) / 256
#define NBLK_TAIL 64

typedef unsigned long long u64;

// ---------------- workspace layout ------------------------------------------
constexpr size_t OFF_PART   = 0;                                   // double x NCHUNK*WW (8 MB)
constexpr size_t OFF_SC64   = OFF_PART   + (size_t)NCHUNK * WW * 8;// double x NB
constexpr size_t OFF_ORDER  = OFF_SC64   + (size_t)NB * 8;         // int x NB
constexpr size_t OFF_CTR    = OFF_ORDER  + (size_t)NB * 4;         // int[2] (64 B pad)
constexpr size_t OFF_IOU    = OFF_CTR    + 64;                     // u64 x NB*16 (128 KB)
constexpr size_t OFF_RECSC  = OFF_IOU    + (size_t)NB * 16 * 8;    // double x NB
constexpr size_t OFF_RECSEL = OFF_RECSC  + (size_t)NB * 8;         // u64 x NB*16 (128 KB)
constexpr size_t OFF_CC     = OFF_RECSEL + (size_t)NB * 16 * 8;    // float x HH*WW (64 MB)
// total ~= 72.5 MB

// ---------------- sc1 (coherent-point) helpers ------------------------------
// Agent-scope RELAXED atomics compile to global_load/store with sc1: they
// bypass the per-XCD L2 and hit the shared coherent point. NO buffer_wbl2 /
// buffer_inv is ever emitted (R1/R2 lesson: those are full-L2 walks, ~1 us
// each, and per-block release/acquire serialized into ~90 us of stall).
template <typename T>
__device__ __forceinline__ T ld_c(const T* p) {
    return __hip_atomic_load(p, __ATOMIC_RELAXED, __HIP_MEMORY_SCOPE_AGENT);
}
template <typename T>
__device__ __forceinline__ void st_c(T* p, T v) {
    __hip_atomic_store(p, v, __ATOMIC_RELAXED, __HIP_MEMORY_SCOPE_AGENT);
}

// fence-free grid barrier for k_tail's 64 co-resident blocks: every thread
// drains its own vmem (so all sc1 stores have reached the coherent point),
// then thread 0 does a relaxed arrival-add and relaxed-polls. Publication is
// ordered by completion (store done -> then arrival visible), so no
// acquire/release cache ops are needed: consumers read via sc1 loads.
__device__ __forceinline__ void gbar(int* bctr, int round) {
    asm volatile("s_waitcnt vmcnt(0)" ::: "memory");
    __syncthreads();
    if (threadIdx.x == 0) {
        __hip_atomic_fetch_add(bctr, 1, __ATOMIC_RELAXED, __HIP_MEMORY_SCOPE_AGENT);
        while (__hip_atomic_load(bctr, __ATOMIC_RELAXED, __HIP_MEMORY_SCOPE_AGENT)
               < NBLK_TAIL * round)
            __builtin_amdgcn_s_sleep(2);
    }
    __syncthreads();
}

// ---------------- kernels ---------------------------------------------------

// staging, PURE (exact R13 body, no sync/atomics — the verified-fast form):
// each block owns one chunk of 16 rows x 1024 cols; derives row x-range
// unions from bbox via LDS atomics; ONE read of probs, float4 loads;
// 1024 blocks = 4 waves/SIMD device-wide. Writes Cc (flagged rows only) and
// per-chunk column sums `part` with normal stores — the k_stage->k_tail
// dispatch boundary provides release/acquire for them.
__global__ void __launch_bounds__(256) k_stage(const float* __restrict__ probs,
        const float* __restrict__ bbox,
        double* __restrict__ part, float* __restrict__ Cc) {
    __shared__ int xlo_s[CROWS], xhi_s[CROWS];
    __shared__ int2 rng_s[CROWS];   // {q0, q1} col-quad range; {1,0} if unflagged
    int tid = blockIdx.x * 256 + threadIdx.x;   // NCHUNK * WW/4 threads
    int c  = tid >> 10;          // chunk (uniform per block)
    int xq = tid & 1023;         // col-quad index
    int t  = threadIdx.x;
    if (t < CROWS) { xlo_s[t] = WW + 1; xhi_s[t] = -1; }
    __syncthreads();
    int r0 = c * CROWS;
    for (int i = t; i < NB; i += 256) {
        float4 bb = ((const float4*)bbox)[i];
        int x1 = min(max((int)floorf(bb.x), 0), WW);
        int y1 = min(max((int)floorf(bb.y), 0), HH);
        int x2 = min(max((int)floorf(bb.z), 0), WW);
        int y2 = min(max((int)floorf(bb.w), 0), HH);
        int ra = y1 - 1 - r0, rb = y2 - 1 - r0;
        if (ra >= 0 && ra < CROWS) { atomicMin(&xlo_s[ra], x1); atomicMax(&xhi_s[ra], x2); }
        if (rb >= 0 && rb < CROWS) { atomicMin(&xlo_s[rb], x1); atomicMax(&xhi_s[rb], x2); }
    }
    __syncthreads();
    if (t < CROWS) {
        int lo = xlo_s[t], hi = xhi_s[t];
        rng_s[t] = (hi >= 0) ? make_int2(lo >> 2, (hi + 3) >> 2) : make_int2(1, 0);
    }
    __syncthreads();
    const float4* p = (const float4*)probs + (size_t)r0 * (WW / 4) + xq;
    float4* Cc4 = (float4*)Cc;
    double a0 = 0.0, a1 = 0.0, a2 = 0.0, a3 = 0.0;
    for (int r = 0; r < CROWS; r += 8) {
        float4 q[8];
        #pragma unroll
        for (int k = 0; k < 8; k++) q[k] = p[(size_t)(r + k) * (WW / 4)];
        #pragma unroll
        for (int k = 0; k < 8; k++) {
            a0 += (double)q[k].x; a1 += (double)q[k].y;
            a2 += (double)q[k].z; a3 += (double)q[k].w;
            int2 d = rng_s[r + k];
            if (xq >= d.x && xq < d.y)
                Cc4[(size_t)(r0 + r + k) * (WW / 4) + xq] =
                    make_float4((float)a0, (float)a1, (float)a2, (float)a3);
        }
    }
    double2* pp = (double2*)(part + (size_t)c * WW) + xq * 2;
    pp[0] = make_double2(a0, a1);
    pp[1] = make_double2(a2, a3);
}

// fused tail: chunkscan -> boxsum -> rank -> iou -> group -> final; one
// kernel, 64 blocks x 256 threads (trivially co-resident on 256 CUs).
// ALL intra-kernel cross-block data goes through sc1 (coherent-point)
// loads/stores; barriers are fence-free (see gbar).
__global__ void __launch_bounds__(256) k_tail(const float* __restrict__ bbox,
        const float* __restrict__ obj,
        const float* __restrict__ Cc,
        double* __restrict__ part,
        const int* __restrict__ counts,
        double* __restrict__ sc64, int* __restrict__ order,
        u64* __restrict__ ioub, double* __restrict__ recsc,
        u64* __restrict__ recsel, int* __restrict__ ctrs,
        float* __restrict__ out) {
    __shared__ double s_sc[NB];     // 8 KB, unsorted scores (P2..P5)
    __shared__ int    ord_s[NB];    // 4 KB, sorted->orig index (P3..P5)
    __shared__ float4 sbb[NB];      // 16 KB, sorted bboxes (P3)
    __shared__ int    rnk[16];
    int b = blockIdx.x, t = threadIdx.x;
    int* bctr = &ctrs[1];

    // ---- P0: per-column exclusive scan of part along the chunk axis.
    // Blocks 0..15, all 256 threads: 16*256 = 4096 columns, 1 col/thread,
    // coalesced. Input via NORMAL loads (fresh: kernel-start invalidate +
    // k_stage's end-of-kernel writeback). Output via sc1 stores (read later
    // by P1 on arbitrary blocks).
    if (b < 16) {
        int x = b * 256 + t;
        double carry = 0.0;
        for (int g = 0; g < NCHUNK / 16; g++) {
            double v[16];
            #pragma unroll
            for (int k = 0; k < 16; k++) v[k] = part[(size_t)(g * 16 + k) * WW + x];
            #pragma unroll
            for (int k = 0; k < 16; k++) { double tv = v[k]; v[k] = carry; carry += tv; }
            #pragma unroll
            for (int k = 0; k < 16; k++)
                st_c(&part[(size_t)(g * 16 + k) * WW + x], v[k]);
        }
    }
    gbar(bctr, 1);

    // ---- P1: boxsum (16 boxes/block, one wave per box, 4 boxes sequential).
    // column value = within-chunk fp32 cumsum row (Cc, normal loads — written
    // only by k_stage) + fp64 chunk prefix (part, sc1 loads — written in P0).
    {
        int wv = t >> 6, l = t & 63;
        for (int q = 0; q < 4; q++) {
            int i = b * 16 + wv * 4 + q;
            float4 bb = ((const float4*)bbox)[i];
            int x1 = min(max((int)floorf(bb.x), 0), WW);
            int y1 = min(max((int)floorf(bb.y), 0), HH);
            int x2 = min(max((int)floorf(bb.z), 0), WW);
            int y2 = min(max((int)floorf(bb.w), 0), HH);
            bool h1 = (y1 >= 1), h2 = (y2 >= 1);
            const float*  r2 = Cc   + (size_t)(h2 ? (y2 - 1) : 0) * WW;
            const double* q2 = part + (size_t)(h2 ? ((y2 - 1) >> 4) : 0) * WW;
            const float*  r1 = Cc   + (size_t)(h1 ? (y1 - 1) : 0) * WW;
            const double* q1 = part + (size_t)(h1 ? ((y1 - 1) >> 4) : 0) * WW;
            double s = 0.0;
            for (int x = x1 + l; x < x2; x += 64) {
                double v2 = h2 ? ((double)r2[x] + ld_c(&q2[x])) : 0.0;
                double v1 = h1 ? ((double)r1[x] + ld_c(&q1[x])) : 0.0;
                s += (v2 - v1);
            }
            #pragma unroll
            for (int off = 32; off > 0; off >>= 1) s += __shfl_down(s, off);
            if (l == 0) {
                long long cnt = (long long)(y2 - y1) * (long long)(x2 - x1);
                if (cnt < 1) cnt = 1;
                st_c(&sc64[i], 0.5 * ((double)obj[i] + s / (double)cnt));
            }
        }
    }
    gbar(bctr, 2);

    // ---- P2: stable descending rank (16 boxes/block, 16 threads per box,
    // 5*g stagger breaks the stride-64-double 16-way LDS bank conflict).
    for (int k = t; k < NB; k += 256) s_sc[k] = ld_c(&sc64[k]);
    if (t < 16) rnk[t] = 0;
    __syncthreads();
    {
        int q = t >> 4;             // box slot 0..15
        int g = t & 15;             // j-chunk 0..15
        int i = b * 16 + q;
        double si = s_sc[i];
        int p = 0;
        for (int it = 0; it < 64; it++) {
            int j = (g << 6) + ((it + 5 * g) & 63);
            double sj = s_sc[j];
            p += (sj > si) || (sj == si && j < i);
        }
        atomicAdd(&rnk[q], p);
    }
    __syncthreads();
    if (t < 16) st_c(&order[rnk[t]], b * 16 + t);
    gbar(bctr, 3);

    // ---- P3: IoU(sorted_i, sorted_j) > 0.5 bit matrix; 16 rows/block,
    // sorted bboxes gathered once into LDS then reused 64x.
    for (int k = t; k < NB; k += 256) {
        int o = ld_c(&order[k]);
        ord_s[k] = o;
        sbb[k] = ((const float4*)bbox)[o];
    }
    __syncthreads();
    {
        int wv = t >> 6, l = t & 63;
        for (int rr = 0; rr < 4; rr++) {
            int i = b * 16 + wv * 4 + rr;
            float4 a = sbb[i];
            float ai = (a.z - a.x) * (a.w - a.y);
            for (int wd = 0; wd < 16; wd++) {
                float4 bb = sbb[(wd << 6) + l];
                float aj = (bb.z - bb.x) * (bb.w - bb.y);
                float ix1 = fmaxf(a.x, bb.x), iy1 = fmaxf(a.y, bb.y);
                float ix2 = fminf(a.z, bb.z), iy2 = fminf(a.w, bb.w);
                float iw = fmaxf(ix2 - ix1, 0.0f), ih = fmaxf(iy2 - iy1, 0.0f);
                float inter = iw * ih;
                float iou_v = inter / (ai + aj - inter);
                u64 m = __ballot(iou_v > IOU_T);
                if (l == 0) st_c(&ioub[(size_t)i * 16 + wd], m);
            }
        }
    }
    gbar(bctr, 4);

    // ---- P4: greedy grouping (16 starts/block, lanes 0..15 of wave 0).
    // Register masks + ctz scan walk the SAME increasing-j greedy order as
    // the reference (inc updated per add). Record rule: rec iff size==K and
    // the last add happened at j <= NB-2 (check-before-add semantics).
    {
        int K = counts[0];
        if (t < 16) {
            int i = b * 16 + t;
            u64 inc[16], sel[16];
            int wi = i >> 6, bi = i & 63;
            #pragma unroll
            for (int w = 0; w < 16; w++) {
                inc[w] = ld_c(&ioub[(size_t)i * 16 + w]);
                sel[w] = (w == wi) ? (1ULL << bi) : 0ULL;
            }
            int size = 1;
            double score = s_sc[ord_s[i]];
            int last = i;
            #pragma unroll
            for (int w = 0; w < 16; w++) {
                if (w < wi || size >= K) continue;
                u64 avail = ~inc[w];
                if (w == wi) avail &= (bi == 63) ? 0ULL : (~0ULL << (bi + 1));
                while (avail != 0ULL && size < K) {
                    int bj = __builtin_ctzll(avail);
                    int j = (w << 6) + bj;
                    sel[w] |= 1ULL << bj;
                    size++;
                    score += s_sc[ord_s[j]];
                    last = j;
                    const u64* rj = ioub + (size_t)j * 16;
                    #pragma unroll
                    for (int w2 = 0; w2 < 16; w2++) inc[w2] |= ld_c(&rj[w2]);
                    avail &= ~inc[w];          // row j's own bits clear bj et al.
                    avail &= ~(1ULL << bj);    // safety
                }
            }
            int rec = (size == K) && (last < NB - 1);
            st_c(&recsc[i], rec ? score : -1e300);
            #pragma unroll
            for (int w = 0; w < 16; w++) st_c(&recsel[(size_t)i * 16 + w], sel[w]);
        }
    }
    gbar(bctr, 5);
    if (b != 0) return;

    // ---- P5: final last-argmax + output scatter (block 0, wave 0).
    if (t < 64) {
        double bs = -1e301; int bidx = 0;
        for (int m = 0; m < 16; m++) {
            int k = t * 16 + m;        // increasing k; >= keeps the last
            double v = ld_c(&recsc[k]);
            if (v >= bs) { bs = v; bidx = k; }
        }
        #pragma unroll
        for (int off = 32; off > 0; off >>= 1) {
            double ob = __shfl_down(bs, off);
            int oi = __shfl_down(bidx, off);
            if (ob > bs || (ob == bs && oi > bidx)) { bs = ob; bidx = oi; }
        }
        bs = __shfl(bs, 0);
        bidx = __shfl(bidx, 0);
        int any = bs > -1e299;
        for (int k = t; k < NB; k += 64) {
            float v = 0.0f;
            if (any && ((ld_c(&recsel[(size_t)bidx * 16 + (k >> 6)]) >> (k & 63)) & 1ULL))
                v = (float)s_sc[ord_s[k]];
            out[k] = v;
        }
    }
}

// ---------------- host entry ------------------------------------------------

extern "C" void kernel_launch(void* const* d_in, const int* in_sizes, int n_in,
                              void* d_out, int out_size, void* d_ws, size_t ws_size,
                              hipStream_t stream) {
    const float* bbox  = (const float*)d_in[0];
    const float* obj   = (const float*)d_in[1];
    const float* probs = (const float*)d_in[2];
    const int*   counts = (const int*)d_in[3];
    float* out = (float*)d_out;

    char* w = (char*)d_ws;
    double* part    = (double*)(w + OFF_PART);
    double* sc64    = (double*)(w + OFF_SC64);
    int*    order   = (int*)(w + OFF_ORDER);
    int*    ctrs    = (int*)(w + OFF_CTR);
    u64*    ioub    = (u64*)(w + OFF_IOU);
    double* recsc   = (double*)(w + OFF_RECSC);
    u64*    recsel  = (u64*)(w + OFF_RECSEL);
    float*  Cc      = (float*)(w + OFF_CC);

    hipMemsetAsync(w + OFF_CTR, 0, 64, stream);   // barrier counters
    k_stage<<<NBLK_STAGE, 256, 0, stream>>>(probs, bbox, part, Cc);
    k_tail<<<NBLK_TAIL, 256, 0, stream>>>(bbox, obj, Cc, part, counts,
                                          sc64, order, ioub, recsc, recsel,
                                          ctrs, out);
}

// Round 4
// 189.030 us; speedup vs baseline: 2.0507x; 1.0078x over previous
//
#include <hip/hip_runtime.h>

// Problem constants (from reference)
#define HH 4096
#define WW 4096
#define NB 1024
#define NCHUNK 256
#define CROWS 16          // HH / NCHUNK
#define NSEG 16           // segments of 16 chunks for the two-level scan
#define IOU_T 0.5f
#define NBLK_STAGE 1024   // (NCHUNK * WW/4) / 256
#define NBLK_TAIL 256     // 1 block/CU — co-residency guaranteed

typedef unsigned long long u64;

// ---------------- workspace layout (~81.5 MB of the 256 MB ws) --------------
constexpr size_t OFF_PART   = 0;                                   // double x NCHUNK*WW (8 MB)
constexpr size_t OFF_SC64   = OFF_PART   + (size_t)NCHUNK * WW * 8;// double x NB
constexpr size_t OFF_ORDER  = OFF_SC64   + (size_t)NB * 8;         // int x NB
constexpr size_t OFF_CTR    = OFF_ORDER  + (size_t)NB * 4;         // int[2] (64 B pad)
constexpr size_t OFF_IOU    = OFF_CTR    + 64;                     // u64 x NB*16 (128 KB)
constexpr size_t OFF_RECSC  = OFF_IOU    + (size_t)NB * 16 * 8;    // double x NB
constexpr size_t OFF_RECSEL = OFF_RECSC  + (size_t)NB * 8;         // u64 x NB*16 (128 KB)
constexpr size_t OFF_CC     = OFF_RECSEL + (size_t)NB * 16 * 8;    // float x HH*WW (64 MB)
constexpr size_t OFF_SEG    = OFF_CC     + (size_t)HH * WW * 4;    // double x NSEG*WW (512 KB)
constexpr size_t OFF_PART2  = OFF_SEG    + (size_t)NSEG * WW * 8;  // double x NCHUNK*WW (8 MB)

// ---------------- sc1 (coherent-point) helpers ------------------------------
// Agent-scope RELAXED atomics compile to global_load/store sc1: bypass the
// per-XCD L2, hit the shared coherent point, emit NO buffer_wbl2/buffer_inv
// (R1/R2 lesson: those are ~1 us full-L2 walks and serialized into ~90 us).
// Discipline (R4): producers of cross-block data use st_c into buffers that
// no XCD has cached earlier in the kernel; consumers then use NORMAL
// (cacheable) loads — they miss L2 and fetch fresh from the coherent point.
template <typename T>
__device__ __forceinline__ T ld_c(const T* p) {
    return __hip_atomic_load(p, __ATOMIC_RELAXED, __HIP_MEMORY_SCOPE_AGENT);
}
template <typename T>
__device__ __forceinline__ void st_c(T* p, T v) {
    __hip_atomic_store(p, v, __ATOMIC_RELAXED, __HIP_MEMORY_SCOPE_AGENT);
}

// fence-free grid barrier (256 co-resident blocks): drain own vmem (sc1
// stores reached the coherent point), relaxed arrival-add, relaxed poll.
__device__ __forceinline__ void gbar(int* bctr, int round) {
    asm volatile("s_waitcnt vmcnt(0)" ::: "memory");
    __syncthreads();
    if (threadIdx.x == 0) {
        __hip_atomic_fetch_add(bctr, 1, __ATOMIC_RELAXED, __HIP_MEMORY_SCOPE_AGENT);
        while (__hip_atomic_load(bctr, __ATOMIC_RELAXED, __HIP_MEMORY_SCOPE_AGENT)
               < NBLK_TAIL * round)
            __builtin_amdgcn_s_sleep(2);
    }
    __syncthreads();
}

// ---------------- kernels ---------------------------------------------------

// staging, PURE (verified R13 body): each block owns one chunk of 16 rows x
// 1024 cols; derives row x-range unions from bbox via LDS atomics; ONE read
// of probs, float4 loads; 1024 blocks = 4 waves/SIMD device-wide. Writes Cc
// (flagged rows only) + per-chunk column sums `part` with normal stores —
// the dispatch boundary to k_tail provides release/acquire.
// Block 0 also zeroes the k_tail barrier counter (saves the memset dispatch).
__global__ void __launch_bounds__(256) k_stage(const float* __restrict__ probs,
        const float* __restrict__ bbox,
        double* __restrict__ part, float* __restrict__ Cc, int* __restrict__ ctrs) {
    __shared__ int xlo_s[CROWS], xhi_s[CROWS];
    __shared__ int2 rng_s[CROWS];   // {q0, q1} col-quad range; {1,0} if unflagged
    int tid = blockIdx.x * 256 + threadIdx.x;   // NCHUNK * WW/4 threads
    int c  = tid >> 10;          // chunk (uniform per block)
    int xq = tid & 1023;         // col-quad index
    int t  = threadIdx.x;
    if (blockIdx.x == 0 && t == 0) st_c(&ctrs[1], 0);
    if (t < CROWS) { xlo_s[t] = WW + 1; xhi_s[t] = -1; }
    __syncthreads();
    int r0 = c * CROWS;
    for (int i = t; i < NB; i += 256) {
        float4 bb = ((const float4*)bbox)[i];
        int x1 = min(max((int)floorf(bb.x), 0), WW);
        int y1 = min(max((int)floorf(bb.y), 0), HH);
        int x2 = min(max((int)floorf(bb.z), 0), WW);
        int y2 = min(max((int)floorf(bb.w), 0), HH);
        int ra = y1 - 1 - r0, rb = y2 - 1 - r0;
        if (ra >= 0 && ra < CROWS) { atomicMin(&xlo_s[ra], x1); atomicMax(&xhi_s[ra], x2); }
        if (rb >= 0 && rb < CROWS) { atomicMin(&xlo_s[rb], x1); atomicMax(&xhi_s[rb], x2); }
    }
    __syncthreads();
    if (t < CROWS) {
        int lo = xlo_s[t], hi = xhi_s[t];
        rng_s[t] = (hi >= 0) ? make_int2(lo >> 2, (hi + 3) >> 2) : make_int2(1, 0);
    }
    __syncthreads();
    const float4* p = (const float4*)probs + (size_t)r0 * (WW / 4) + xq;
    float4* Cc4 = (float4*)Cc;
    double a0 = 0.0, a1 = 0.0, a2 = 0.0, a3 = 0.0;
    for (int r = 0; r < CROWS; r += 8) {
        float4 q[8];
        #pragma unroll
        for (int k = 0; k < 8; k++) q[k] = p[(size_t)(r + k) * (WW / 4)];
        #pragma unroll
        for (int k = 0; k < 8; k++) {
            a0 += (double)q[k].x; a1 += (double)q[k].y;
            a2 += (double)q[k].z; a3 += (double)q[k].w;
            int2 d = rng_s[r + k];
            if (xq >= d.x && xq < d.y)
                Cc4[(size_t)(r0 + r + k) * (WW / 4) + xq] =
                    make_float4((float)a0, (float)a1, (float)a2, (float)a3);
        }
    }
    double2* pp = (double2*)(part + (size_t)c * WW) + xq * 2;
    pp[0] = make_double2(a0, a1);
    pp[1] = make_double2(a2, a3);
}

// fused tail: segscan -> boxsum -> rank -> iou -> group -> final; one kernel,
// 256 blocks x 256 threads (1/CU). All cross-block producer stores go via
// sc1 into fresh buffers; consumers use normal cacheable loads (see helpers).
__global__ void __launch_bounds__(256) k_tail(const float* __restrict__ bbox,
        const float* __restrict__ obj,
        const float* __restrict__ Cc,
        const double* __restrict__ part,
        double* __restrict__ segsum, double* __restrict__ part2,
        const int* __restrict__ counts,
        double* __restrict__ sc64, int* __restrict__ order,
        u64* __restrict__ ioub, double* __restrict__ recsc,
        u64* __restrict__ recsel, int* __restrict__ ctrs,
        float* __restrict__ out) {
    __shared__ double s_sc[NB];     // 8 KB, unsorted scores (P2..P5)
    __shared__ int    ord_s[NB];    // 4 KB, sorted->orig index (P3..P5)
    __shared__ float4 sbb[NB];      // 16 KB, sorted bboxes (P3)
    __shared__ int    rnk[4];
    int b = blockIdx.x, t = threadIdx.x;
    int gtid = b * 256 + t;         // 0..65535
    int* bctr = &ctrs[1];

    // ---- P0a: segment sums of part. 65536 threads on 65536 (seg,col) tasks;
    // seg uniform per block, col coalesced. part read normal (k_stage data).
    {
        int col = gtid & (WW - 1);
        int seg = gtid >> 12;       // 0..15
        const double* pp = part + (size_t)seg * CROWS * WW + col;
        double s = 0.0;
        #pragma unroll
        for (int k = 0; k < 16; k++) s += pp[(size_t)k * WW];
        st_c(&segsum[(size_t)seg * WW + col], s);
    }
    gbar(bctr, 1);

    // ---- P0b: per-thread carry = prefix of segsums (normal loads, fresh
    // buffer), then local exclusive scan of 16 part values (L2-hot from P0a,
    // same block) into part2 (sc1). part itself is never overwritten.
    {
        int col = gtid & (WW - 1);
        int seg = gtid >> 12;
        double carry = 0.0;
        for (int s = 0; s < seg; s++) carry += segsum[(size_t)s * WW + col];
        const double* pp = part  + (size_t)seg * CROWS * WW + col;
        double*       qq = part2 + (size_t)seg * CROWS * WW + col;
        #pragma unroll
        for (int k = 0; k < 16; k++) {
            double v = pp[(size_t)k * WW];
            st_c(&qq[(size_t)k * WW], carry);
            carry += v;
        }
    }
    gbar(bctr, 2);

    // ---- P1: boxsum, ONE box per wave (1024 waves device-wide). Column
    // value = within-chunk fp32 cumsum row (Cc) + fp64 chunk prefix (part2),
    // both normal cacheable loads.
    {
        int wv = t >> 6, l = t & 63;
        int i = b * 4 + wv;
        float4 bb = ((const float4*)bbox)[i];
        int x1 = min(max((int)floorf(bb.x), 0), WW);
        int y1 = min(max((int)floorf(bb.y), 0), HH);
        int x2 = min(max((int)floorf(bb.z), 0), WW);
        int y2 = min(max((int)floorf(bb.w), 0), HH);
        bool h1 = (y1 >= 1), h2 = (y2 >= 1);
        const float*  r2 = Cc    + (size_t)(h2 ? (y2 - 1) : 0) * WW;
        const double* q2 = part2 + (size_t)(h2 ? ((y2 - 1) >> 4) : 0) * WW;
        const float*  r1 = Cc    + (size_t)(h1 ? (y1 - 1) : 0) * WW;
        const double* q1 = part2 + (size_t)(h1 ? ((y1 - 1) >> 4) : 0) * WW;
        double s = 0.0;
        for (int x = x1 + l; x < x2; x += 64) {
            double v2 = h2 ? ((double)r2[x] + q2[x]) : 0.0;
            double v1 = h1 ? ((double)r1[x] + q1[x]) : 0.0;
            s += (v2 - v1);
        }
        #pragma unroll
        for (int off = 32; off > 0; off >>= 1) s += __shfl_down(s, off);
        if (l == 0) {
            long long cnt = (long long)(y2 - y1) * (long long)(x2 - x1);
            if (cnt < 1) cnt = 1;
            st_c(&sc64[i], 0.5 * ((double)obj[i] + s / (double)cnt));
        }
    }
    gbar(bctr, 3);

    // ---- P2: stable descending rank; 4 boxes/block, 64 threads per box,
    // 16 j's per thread with +g rotation (bank spread on the LDS reads).
    for (int k = t; k < NB; k += 256) s_sc[k] = sc64[k];     // normal loads
    if (t < 4) rnk[t] = 0;
    __syncthreads();
    {
        int q = t >> 6;             // box slot 0..3
        int g = t & 63;             // j-chunk of 16
        int i = b * 4 + q;
        double si = s_sc[i];
        int p = 0;
        #pragma unroll
        for (int it = 0; it < 16; it++) {
            int j = (g << 4) + ((it + g) & 15);
            double sj = s_sc[j];
            p += (sj > si) || (sj == si && j < i);
        }
        atomicAdd(&rnk[q], p);
    }
    __syncthreads();
    if (t < 4) st_c(&order[rnk[t]], b * 4 + t);
    gbar(bctr, 4);

    // ---- P3: IoU(sorted_i, sorted_j) > 0.5 bit matrix; 4 rows/block (one
    // per wave); sorted bboxes gathered once into LDS, reused 64x.
    for (int k = t; k < NB; k += 256) {
        int o = order[k];           // normal load (fresh buffer)
        ord_s[k] = o;
        sbb[k] = ((const float4*)bbox)[o];
    }
    __syncthreads();
    {
        int wv = t >> 6, l = t & 63;
        int i = b * 4 + wv;
        float4 a = sbb[i];
        float ai = (a.z - a.x) * (a.w - a.y);
        for (int wd = 0; wd < 16; wd++) {
            float4 bb = sbb[(wd << 6) + l];
            float aj = (bb.z - bb.x) * (bb.w - bb.y);
            float ix1 = fmaxf(a.x, bb.x), iy1 = fmaxf(a.y, bb.y);
            float ix2 = fminf(a.z, bb.z), iy2 = fminf(a.w, bb.w);
            float iw = fmaxf(ix2 - ix1, 0.0f), ih = fmaxf(iy2 - iy1, 0.0f);
            float inter = iw * ih;
            float iou_v = inter / (ai + aj - inter);
            u64 m = __ballot(iou_v > IOU_T);
            if (l == 0) st_c(&ioub[(size_t)i * 16 + wd], m);
        }
    }
    gbar(bctr, 5);

    // ---- P4: greedy grouping, 4 starts/block (threads 0..3), normal
    // cacheable loads of ioub (fresh buffer; row reads L2-amortized).
    // Register masks + ctz scan walk the SAME increasing-j greedy order as
    // the reference (inc updated per add). Record rule: rec iff size==K and
    // the last add happened at j <= NB-2 (check-before-add semantics).
    {
        int K = counts[0];
        if (t < 4) {
            int i = b * 4 + t;
            u64 inc[16], sel[16];
            int wi = i >> 6, bi = i & 63;
            #pragma unroll
            for (int w = 0; w < 16; w++) {
                inc[w] = ioub[(size_t)i * 16 + w];
                sel[w] = (w == wi) ? (1ULL << bi) : 0ULL;
            }
            int size = 1;
            double score = s_sc[ord_s[i]];
            int last = i;
            #pragma unroll
            for (int w = 0; w < 16; w++) {
                if (w < wi || size >= K) continue;
                u64 avail = ~inc[w];
                if (w == wi) avail &= (bi == 63) ? 0ULL : (~0ULL << (bi + 1));
                while (avail != 0ULL && size < K) {
                    int bj = __builtin_ctzll(avail);
                    int j = (w << 6) + bj;
                    sel[w] |= 1ULL << bj;
                    size++;
                    score += s_sc[ord_s[j]];
                    last = j;
                    const u64* rj = ioub + (size_t)j * 16;
                    #pragma unroll
                    for (int w2 = 0; w2 < 16; w2++) inc[w2] |= rj[w2];
                    avail &= ~inc[w];          // row j's own bits clear bj et al.
                    avail &= ~(1ULL << bj);    // safety
                }
            }
            int rec = (size == K) && (last < NB - 1);
            st_c(&recsc[i], rec ? score : -1e300);
            #pragma unroll
            for (int w = 0; w < 16; w++) st_c(&recsel[(size_t)i * 16 + w], sel[w]);
        }
    }
    gbar(bctr, 6);
    if (b != 0) return;

    // ---- P5: final last-argmax + output scatter (block 0, wave 0).
    if (t < 64) {
        double bs = -1e301; int bidx = 0;
        for (int m = 0; m < 16; m++) {
            int k = t * 16 + m;        // increasing k; >= keeps the last
            double v = recsc[k];       // normal load (fresh buffer)
            if (v >= bs) { bs = v; bidx = k; }
        }
        #pragma unroll
        for (int off = 32; off > 0; off >>= 1) {
            double ob = __shfl_down(bs, off);
            int oi = __shfl_down(bidx, off);
            if (ob > bs || (ob == bs && oi > bidx)) { bs = ob; bidx = oi; }
        }
        bs = __shfl(bs, 0);
        bidx = __shfl(bidx, 0);
        int any = bs > -1e299;
        for (int k = t; k < NB; k += 64) {
            float v = 0.0f;
            if (any && ((recsel[(size_t)bidx * 16 + (k >> 6)] >> (k & 63)) & 1ULL))
                v = (float)s_sc[ord_s[k]];
            out[k] = v;
        }
    }
}

// ---------------- host entry ------------------------------------------------

extern "C" void kernel_launch(void* const* d_in, const int* in_sizes, int n_in,
                              void* d_out, int out_size, void* d_ws, size_t ws_size,
                              hipStream_t stream) {
    const float* bbox  = (const float*)d_in[0];
    const float* obj   = (const float*)d_in[1];
    const float* probs = (const float*)d_in[2];
    const int*   counts = (const int*)d_in[3];
    float* out = (float*)d_out;

    char* w = (char*)d_ws;
    double* part    = (double*)(w + OFF_PART);
    double* sc64    = (double*)(w + OFF_SC64);
    int*    order   = (int*)(w + OFF_ORDER);
    int*    ctrs    = (int*)(w + OFF_CTR);
    u64*    ioub    = (u64*)(w + OFF_IOU);
    double* recsc   = (double*)(w + OFF_RECSC);
    u64*    recsel  = (u64*)(w + OFF_RECSEL);
    float*  Cc      = (float*)(w + OFF_CC);
    double* segsum  = (double*)(w + OFF_SEG);
    double* part2   = (double*)(w + OFF_PART2);

    k_stage<<<NBLK_STAGE, 256, 0, stream>>>(probs, bbox, part, Cc, ctrs);
    k_tail<<<NBLK_TAIL, 256, 0, stream>>>(bbox, obj, Cc, part, segsum, part2,
                                          counts, sc64, order, ioub, recsc,
                                          recsel, ctrs, out);
}